// Round 8
// baseline (468.790 us; speedup 1.0000x reference)
//
#include <hip/hip_runtime.h>

// Problem constants (fixed by reference): B=2, N=8192, C=80
constexpr int NB = 2;
constexpr int NN = 8192;
constexpr int NC = 80;
constexpr int ROWS = NN + 1;  // mask rows per batch; row NN is an all-zero row

// d_out layout (floats), in reference return order:
// boxes[B,N,4], max_scores[B,N], labels[B,N], keep[B,N], all_scores[B,N,C]
constexpr size_t OFF_BOXES  = 0;
constexpr size_t OFF_SCORES = (size_t)NB * NN * 4;
constexpr size_t OFF_LABELS = OFF_SCORES + (size_t)NB * NN;
constexpr size_t OFF_KEEP   = OFF_LABELS + (size_t)NB * NN;
constexpr size_t OFF_ALL    = OFF_KEEP + (size_t)NB * NN;

// d_ws layout
constexpr size_t WS_KEYS  = 0;                                   // B*N u64
constexpr size_t WS_VBYTE = WS_KEYS + (size_t)NB * NN * 8;       // B*N u8
constexpr size_t WS_ORDER = WS_VBYTE + (size_t)NB * NN;          // B*N i32
constexpr size_t WS_SBOX  = WS_ORDER + (size_t)NB * NN * 4;      // B*N float4
constexpr size_t WS_VBITS = WS_SBOX + (size_t)NB * NN * 16;      // B*128 u64
constexpr size_t WS_MASK  = WS_VBITS + (size_t)NB * 128 * 8;     // B*ROWS*128 u64
constexpr size_t WS_DNM   = WS_MASK + (size_t)NB * ROWS * 128 * 8; // B*128*8*64 u64
constexpr size_t WS_TOTAL = WS_DNM + (size_t)NB * 128 * 8 * 64 * 8;
constexpr int DNM_WORDS = NB * 128 * 8 * 64;  // 131072

typedef unsigned long long u64;

// lgkmcnt(0)-only barrier: keeps global loads in flight across it.
// simm16: vmcnt[3:0]=0xF, expcnt=7<<4, lgkmcnt=0<<8, vmcnt[5:4]=3<<14 -> 0xC07F
__device__ inline void lbar() {
  __builtin_amdgcn_s_waitcnt(0xc07f);
  __builtin_amdgcn_s_barrier();
}

__device__ inline u64 readlane64(u64 v, int src) {
  unsigned int lo = (unsigned int)__builtin_amdgcn_readlane((int)(unsigned int)v, src);
  unsigned int hi = (unsigned int)__builtin_amdgcn_readlane((int)(unsigned int)(v >> 32), src);
  return ((u64)hi << 32) | lo;
}

__device__ inline u64 readfirstlane64(u64 v) {
  unsigned int lo = (unsigned int)__builtin_amdgcn_readfirstlane((int)(unsigned int)v);
  unsigned int hi = (unsigned int)__builtin_amdgcn_readfirstlane((int)(unsigned int)(v >> 32));
  return ((u64)hi << 32) | lo;
}

// IoU exactly mirroring the numpy op order; contraction off so f32 rounding
// matches numpy bit-for-bit (keep bits tolerate no error).
__device__ inline float iou_pair(const float4 p, const float4 q) {
#pragma clang fp contract(off)
  float areaA = (p.z - p.x) * (p.w - p.y);
  float areaB = (q.z - q.x) * (q.w - q.y);
  float ix1 = fmaxf(p.x, q.x);
  float iy1 = fmaxf(p.y, q.y);
  float ix2 = fminf(p.z, q.z);
  float iy2 = fminf(p.w, q.w);
  float inter = fmaxf(ix2 - ix1, 0.0f) * fmaxf(iy2 - iy1, 0.0f);
  float uni = areaA + areaB - inter;
  return inter / fmaxf(uni, 1e-9f);
}

__device__ inline float clip01(float v) { return fminf(fmaxf(v, 0.0f), 1.0f); }

// One wave per (b,n): sigmoid all 80 classes, max/argmax (first-index ties),
// box decode, validity, sort key. Also zero-inits vbits.
__global__ __launch_bounds__(256) void decode_kernel(
    const float* __restrict__ logits, const float4* __restrict__ deltas,
    const float4* __restrict__ anchors, float4* __restrict__ boxes_out,
    float* __restrict__ scores_out, float* __restrict__ labels_out,
    float* __restrict__ all_out, u64* __restrict__ keys,
    unsigned char* __restrict__ vbyte, u64* __restrict__ vbits) {
#pragma clang fp contract(off)
  if (blockIdx.x == 0 && threadIdx.x < NB * 128) vbits[threadIdx.x] = 0ull;
  int wid = (blockIdx.x * 256 + threadIdx.x) >> 6;  // 0 .. B*N-1
  int lane = threadIdx.x & 63;
  int n = wid & (NN - 1);
  size_t base = (size_t)wid * NC;

  float x0 = logits[base + lane];
  float sig0 = 1.0f / (1.0f + expf(-x0));
  all_out[base + lane] = sig0;
  float bs = sig0;
  int bidx = lane;
  if (lane < NC - 64) {
    float x1 = logits[base + 64 + lane];
    float sig1 = 1.0f / (1.0f + expf(-x1));
    all_out[base + 64 + lane] = sig1;
    if (sig1 > bs) { bs = sig1; bidx = lane + 64; }  // tie -> smaller idx wins
  }
  for (int off = 32; off; off >>= 1) {
    float os = __shfl_xor(bs, off, 64);
    int oi = __shfl_xor(bidx, off, 64);
    if (os > bs || (os == bs && oi < bidx)) { bs = os; bidx = oi; }
  }
  if (lane == 0) {
    float4 d = deltas[wid];
    float4 a = anchors[n];
    float aw = a.z - a.x, ah = a.w - a.y;
    float acx = a.x + 0.5f * aw, acy = a.y + 0.5f * ah;
    float dw = fminf(d.z, 4.0f), dh = fminf(d.w, 4.0f);
    float pcx = d.x * aw + acx;
    float pcy = d.y * ah + acy;
    float pw = expf(dw) * aw;
    float ph = expf(dh) * ah;
    float4 bx;
    bx.x = clip01(pcx - 0.5f * pw);
    bx.y = clip01(pcy - 0.5f * ph);
    bx.z = clip01(pcx + 0.5f * pw);
    bx.w = clip01(pcy + 0.5f * ph);
    boxes_out[wid] = bx;
    scores_out[wid] = bs;
    labels_out[wid] = (float)bidx;
    float bw = bx.z - bx.x, bh = bx.w - bx.y;
    bool valid = (bs > 0.5f) && (bw > 0.01f) && (bh > 0.01f) &&
                 (bw < 0.99f) && (bh < 0.99f);
    vbyte[wid] = valid ? 1 : 0;
    // score bits monotone (score>0); tie-break: smaller n first under
    // DESCENDING key sort -> (N-1-n) in low bits. Keys are UNIQUE.
    keys[wid] = ((u64)__float_as_uint(bs) << 32) | (unsigned int)(NN - 1 - n);
  }
}

// Rank sort: rank_i = #{j: key_j > key_i} (keys unique -> permutation).
// Block = 1024 threads = 256 rows x 4 column-quarters; column index is
// wave-uniform -> key loads scalarize. Also zero-inits dnm.
__global__ __launch_bounds__(1024) void rank_kernel(
    const u64* __restrict__ keys, const float4* __restrict__ boxes,
    const unsigned char* __restrict__ vbyte, int* __restrict__ order,
    float4* __restrict__ sbox, u64* __restrict__ vbits,
    u64* __restrict__ dnm) {
  int b = blockIdx.y;
  int gid = (blockIdx.y * gridDim.x + blockIdx.x) * 1024 + threadIdx.x;
  for (int z = gid; z < DNM_WORDS; z += 65536) dnm[z] = 0ull;
  int r = threadIdx.x & 255;   // row slot
  int q = threadIdx.x >> 8;    // column quarter 0..3
  int i = blockIdx.x * 256 + r;
  const u64* kb = keys + (size_t)b * NN;
  u64 myk = kb[i];
  int cnt = 0;
  int j0 = q * (NN / 4), j1 = j0 + NN / 4;
#pragma unroll 8
  for (int j = j0; j < j1; ++j) {
    u64 kj = kb[j];  // wave-uniform address -> scalar load
    cnt += (kj > myk) ? 1 : 0;
  }
  __shared__ unsigned short part[4][256];
  part[q][r] = (unsigned short)cnt;
  __syncthreads();
  if (threadIdx.x < 256) {
    int rank = part[0][r] + part[1][r] + part[2][r] + part[3][r];
    order[(size_t)b * NN + rank] = i;
    sbox[(size_t)b * NN + rank] = boxes[(size_t)b * NN + i];
    if (vbyte[(size_t)b * NN + i])
      atomicOr(&vbits[b * 128 + (rank >> 6)], 1ull << (rank & 63));
  }
}

// 64x64 tile of the (sorted-order) suppression matrix: bit j set in row i's
// word iff j>i and IoU>0.5. Upper triangle only. Tiles with bx-by in {0..7}
// also write the COMPACT dnm array (8 diagonals: words c..c+7 of each row in
// chunk c) so reduce's wave 0 prefetches with coalesced 512B loads.
__global__ __launch_bounds__(64) void build_kernel(
    const float4* __restrict__ sbox, u64* __restrict__ mask,
    u64* __restrict__ dnm) {
  int bx = blockIdx.x, by = blockIdx.y, b = blockIdx.z;
  if (bx < by) return;
  int lane = threadIdx.x;
  __shared__ float4 cb[64];
  cb[lane] = sbox[(size_t)b * NN + bx * 64 + lane];
  __syncthreads();
  int i = by * 64 + lane;
  float4 rb = sbox[(size_t)b * NN + i];
  u64 word = 0;
  int j0 = (bx == by) ? lane + 1 : 0;
  for (int jj = j0; jj < 64; ++jj)
    if (iou_pair(rb, cb[jj]) > 0.5f) word |= 1ull << jj;
  mask[((size_t)b * ROWS + i) * 128 + bx] = word;
  int dq = bx - by;
  if (dq < 8) dnm[(((size_t)b * 128 + by) * 8 + dq) * 64 + lane] = word;
}

// Greedy reduce v8: one 512-thread block per batch; 256-box window (4
// chunks) per barrier round -> 32 lgkm-only barriers instead of 128.
//  - Wave 0: per round, serially process 4 sub-chunks. Diag+7 words of every
//    row come from the compact dnm (32 coalesced loads/round, prefetched one
//    full round ahead into ping-ponged register banks W0/W1, static indices
//    only). Kept lanes deposit words c+1 .. 4r+7 (rest of window + whole
//    next window) via LDS atomicOr; sub-chunk boundary = one LDS round-trip.
//  - Waves 1..7 (background): during round r, OR rows kept at round r-1
//    into s_remv words >= 4r+4 (grouped 4-wide coalesced loads, issue and
//    consume in-round). Word partition with wave 0 is exact: wave 0 covers
//    <= 4(r-1)+7 = 4r+3 during round r-1, bg covers >= 4r+4 during round r,
//    both strictly before round r+1 reads window r+1.
__global__ __launch_bounds__(512) void reduce_kernel(
    u64* __restrict__ mask, const u64* __restrict__ vbits,
    const u64* __restrict__ dnm, const int* __restrict__ order,
    float* __restrict__ keep_out) {
  int b = blockIdx.x, tid = threadIdx.x;
  int lane = tid & 63, wave = tid >> 6;
  __shared__ u64 s_remv[128];
  __shared__ u64 s_keep[128];
  __shared__ int s_rowlist[2][256];
  __shared__ int s_nk[2];
  u64* mbz = mask + (size_t)b * ROWS * 128;
  const u64* mb = mbz;
  const u64* dn = dnm + (size_t)b * 128 * 8 * 64;

  for (int w = tid; w < 128; w += 512) {
    s_remv[w] = 0ull;
    mbz[(size_t)NN * 128 + w] = 0ull;  // zero row (padded bg target)
  }
  if (tid < 2) s_nk[tid] = 0;

  // Wave 0 state: vbits in regs; ping-pong window banks W0/W1 (4 chunks x 8
  // diagonal words each, all statically indexed).
  u64 va = 0, vb2 = 0;
  u64 W0[4][8], W1[4][8];
#pragma unroll
  for (int g = 0; g < 4; ++g)
#pragma unroll
    for (int s = 0; s < 8; ++s) { W0[g][s] = 0; W1[g][s] = 0; }
  if (wave == 0) {
    va = vbits[b * 128 + 2 * lane];
    vb2 = vbits[b * 128 + 2 * lane + 1];
#pragma unroll
    for (int g = 0; g < 4; ++g)
#pragma unroll
      for (int s = 0; s < 8; ++s)
        W0[g][s] = dn[((size_t)g * 8 + s) * 64 + lane];
  }
  int w0i = 2 * lane, w1i = 2 * lane + 1;
  __syncthreads();  // full barrier: zero-row global write + LDS init visible

  auto serial_body = [&](int rnd, u64 (&Wc)[4][8], u64 (&Wn)[4][8]) {
    int base = rnd * 4;
    // prefetch next window (consumed after the next barrier -> full-round
    // slack for the waitcnt)
    if (rnd + 1 < 32) {
#pragma unroll
      for (int g = 0; g < 4; ++g)
#pragma unroll
        for (int s = 0; s < 8; ++s)
          Wn[g][s] = dn[((size_t)(base + 4 + g) * 8 + s) * 64 + lane];
    }
    int kbase = 0;
    int par = rnd & 1;
#pragma unroll
    for (int g = 0; g < 4; ++g) {
      int c = base + g;
      u64 rm = readfirstlane64(s_remv[c]);  // broadcast LDS read -> scalar
      u64 vbw = readlane64((c & 1) ? vb2 : va, c >> 1);
      u64 cand = vbw & ~rm;
      u64 kept = 0;
      while (cand) {  // scalar loop; one iteration per KEPT box
        int bi = (int)__builtin_ctzll(cand);
        u64 rd = readlane64(Wc[g][0], bi);  // diag word of kept row
        kept |= 1ull << bi;
        cand = (cand - 1) & cand & ~rd;
      }
      bool isk = (kept >> lane) & 1;
      // kept lanes deposit words c+1 .. base+7 (rest of window + next window)
#pragma unroll
      for (int s = 1; s <= 7; ++s) {
        if (s <= 7 - g) {
          u64 v = Wc[g][s];
          if (isk && v && c + s < 128) atomicOr(&s_remv[c + s], v);
        }
      }
      if (isk) {
        int pos = kbase + __popcll(kept & ((1ull << lane) - 1ull));
        s_rowlist[par][pos] = c * 64 + lane;
      }
      if (lane == 0) s_keep[c] = kept;
      kbase += __popcll(kept);
    }
    if (lane == 0) s_nk[par] = kbase;
  };

  auto bg_body = [&](int rnd) {
    int nk1 = s_nk[(rnd - 1) & 1];  // rnd=0 -> slot 1 = 0
    if (nk1 <= 0) return;
    const int* rl = s_rowlist[(rnd - 1) & 1];
    int gate = rnd * 4 + 4;  // words >= 4r+4 are bg's responsibility
    u64 ax = 0, ay = 0;
    for (int s = wave - 1; s < nk1; s += 28) {  // waves 1..7, 4-wide groups
      int r0 = rl[s];
      int r1 = (s + 7 < nk1) ? rl[s + 7] : NN;
      int r2 = (s + 14 < nk1) ? rl[s + 14] : NN;
      int r3 = (s + 21 < nk1) ? rl[s + 21] : NN;
      ulonglong2 v0 = *(const ulonglong2*)(mb + (size_t)r0 * 128 + w0i);
      ulonglong2 v1 = *(const ulonglong2*)(mb + (size_t)r1 * 128 + w0i);
      ulonglong2 v2 = *(const ulonglong2*)(mb + (size_t)r2 * 128 + w0i);
      ulonglong2 v3 = *(const ulonglong2*)(mb + (size_t)r3 * 128 + w0i);
      ax |= v0.x | v1.x | v2.x | v3.x;
      ay |= v0.y | v1.y | v2.y | v3.y;
    }
    if (w0i >= gate && ax) atomicOr(&s_remv[w0i], ax);
    if (w1i >= gate && ay) atomicOr(&s_remv[w1i], ay);
  };

  for (int r = 0; r < 32; r += 2) {
    if (wave == 0) serial_body(r, W0, W1);
    else bg_body(r);
    lbar();
    if (wave == 0) serial_body(r + 1, W1, W0);
    else bg_body(r + 1);
    lbar();
  }

  // scatter keep flags back to original anchor order
  for (int p = tid; p < NN; p += 512) {
    int orig = order[(size_t)b * NN + p];
    keep_out[(size_t)b * NN + orig] =
        ((s_keep[p >> 6] >> (p & 63)) & 1) ? 1.0f : 0.0f;
  }
}

// Slow-but-correct fallback if d_ws can't hold the mask: classic iterative
// greedy NMS, one block per batch.
__global__ __launch_bounds__(1024) void nms_fallback(
    const float4* __restrict__ sbox, const u64* __restrict__ vbits,
    const int* __restrict__ order, float* __restrict__ keep_out) {
  int b = blockIdx.x, tid = threadIdx.x;
  __shared__ u64 dead[128];
  __shared__ int s_next;
  __shared__ float4 s_box;
  for (int w = tid; w < 128; w += 1024) dead[w] = ~vbits[b * 128 + w];
  for (int p = tid; p < NN; p += 1024)
    keep_out[(size_t)b * NN + order[(size_t)b * NN + p]] = 0.0f;
  __syncthreads();
  int i = 0;
  while (true) {
    if (tid == 0) {
      int nxt = NN;
      int w = i >> 6;
      u64 live = ~dead[w] & (~0ull << (i & 63));
      while (true) {
        if (live) { nxt = w * 64 + __builtin_ctzll(live); break; }
        if (++w >= 128) break;
        live = ~dead[w];
      }
      s_next = nxt;
      if (nxt < NN) {
        s_box = sbox[(size_t)b * NN + nxt];
        keep_out[(size_t)b * NN + order[(size_t)b * NN + nxt]] = 1.0f;
      }
    }
    __syncthreads();
    i = s_next;
    if (i >= NN) break;
    float4 kb = s_box;
    for (int j = i + 1 + tid; j < NN; j += 1024) {
      if (iou_pair(kb, sbox[(size_t)b * NN + j]) > 0.5f)
        atomicOr(&dead[j >> 6], 1ull << (j & 63));
    }
    __syncthreads();
    i = i + 1;
  }
}

extern "C" void kernel_launch(void* const* d_in, const int* in_sizes, int n_in,
                              void* d_out, int out_size, void* d_ws, size_t ws_size,
                              hipStream_t stream) {
  const float* logits = (const float*)d_in[0];
  const float4* deltas = (const float4*)d_in[1];
  const float4* anchors = (const float4*)d_in[2];
  float* out = (float*)d_out;
  float4* boxes_out = (float4*)(out + OFF_BOXES);
  float* scores_out = out + OFF_SCORES;
  float* labels_out = out + OFF_LABELS;
  float* keep_out = out + OFF_KEEP;
  float* all_out = out + OFF_ALL;

  char* ws = (char*)d_ws;
  u64* keys = (u64*)(ws + WS_KEYS);
  unsigned char* vbyte = (unsigned char*)(ws + WS_VBYTE);
  int* order = (int*)(ws + WS_ORDER);
  float4* sbox = (float4*)(ws + WS_SBOX);
  u64* vbits = (u64*)(ws + WS_VBITS);
  u64* mask = (u64*)(ws + WS_MASK);
  u64* dnm = (u64*)(ws + WS_DNM);

  decode_kernel<<<dim3(NB * NN / 4), dim3(256), 0, stream>>>(
      logits, deltas, anchors, boxes_out, scores_out, labels_out, all_out,
      keys, vbyte, vbits);
  rank_kernel<<<dim3(NN / 256, NB), dim3(1024), 0, stream>>>(
      keys, (const float4*)boxes_out, vbyte, order, sbox, vbits, dnm);
  if (ws_size >= WS_TOTAL) {
    build_kernel<<<dim3(128, 128, NB), dim3(64), 0, stream>>>(sbox, mask, dnm);
    reduce_kernel<<<dim3(NB), dim3(512), 0, stream>>>(mask, vbits, dnm, order,
                                                      keep_out);
  } else {
    nms_fallback<<<dim3(NB), dim3(1024), 0, stream>>>(sbox, vbits, order,
                                                      keep_out);
  }
}